// Round 9
// baseline (141.943 us; speedup 1.0000x reference)
//
#include <hip/hip_runtime.h>

#define NN 4
#define CC 32
#define LL 8
#define DD 24
#define HH 24
#define WW 24

typedef short  bf16x8  __attribute__((ext_vector_type(8)));
typedef float  f32x16  __attribute__((ext_vector_type(16)));
typedef unsigned short ushort8 __attribute__((ext_vector_type(8)));

// ws layout (36,161,536 B):
//   xp: [cig 2][n 4][l 8][dp 26][hp 26][wp 26][ci 16] bf16, NO padding
//   Ag: [cig 2][ql 3][qd 3][s 9][lane 64][j 8] bf16 (flipped wgt, frag order)
#define XP_CHUNKS 2249728            // 16B chunks
#define XP_ELEMS  (XP_CHUNKS * 8)
#define AG_ELEMS  82944

__device__ __forceinline__ unsigned short f2bf(float f) {
    union { float f; unsigned u; } v; v.f = f;
    unsigned r = v.u + 0x7FFFu + ((v.u >> 16) & 1u);   // RNE
    return (unsigned short)(r >> 16);
}

__device__ __forceinline__ void gload16(const void* g, void* l) {
    __builtin_amdgcn_global_load_lds(
        (const __attribute__((address_space(1))) unsigned int*)g,
        (__attribute__((address_space(3))) unsigned int*)l, 16, 0, 0);
}

// ---- fused pre-pass: x -> xp and wgt -> Ag (verified R5-R7) ----
__global__ __launch_bounds__(256) void prep(const float* __restrict__ x,
                                            const float* __restrict__ wgt,
                                            unsigned short* __restrict__ xp,
                                            unsigned short* __restrict__ Ag) {
    const int id = blockIdx.x * 256 + threadIdx.x;
    if (id < XP_CHUNKS) {
        const int wp = id % 26;
        const int r  = id / 26;
        const int g  = r & 1;
        const int r2 = r >> 1;             // slab*26 + hp
        const int hp = r2 % 26;
        const int slab = r2 / 26;          // ((cig*4 + n)*8 + l)*26 + dp
        const int dp = slab % 26;
        const int s2 = slab / 26;
        const int l  = s2 & 7;
        const int n  = (s2 >> 3) & 3;
        const int cig = s2 >> 5;
        const int dx = dp - 1, hx = hp - 1, wx = wp - 1;
        ushort8 v = {0, 0, 0, 0, 0, 0, 0, 0};
        if ((unsigned)dx < DD && (unsigned)hx < HH && (unsigned)wx < WW) {
            const int ci0 = cig * 16 + g * 8;
            const float* src = x + ((((size_t)n * CC + ci0) * LL + l) * DD + dx) * (HH * WW)
                             + hx * WW + wx;
#pragma unroll
            for (int ci = 0; ci < 8; ++ci)
                v[ci] = f2bf(src[(size_t)ci * (LL * DD * HH * WW)]);
        }
        const size_t dstc = ((size_t)r2 * 26 + wp) * 2 + g;
        *reinterpret_cast<ushort8*>(xp + dstc * 8) = v;
    } else {
        const int i = id - XP_CHUNKS;
        if (i < AG_ELEMS) {
            const int j  = i & 7;
            const int ln = (i >> 3) & 63;
            const int rest = i >> 9;       // 0..161
            const int s  = rest % 9;
            const int r  = rest / 9;       // cig*9 + ql*3 + qd
            const int qd = r % 3;
            const int ql = (r / 3) % 3;
            const int cig = r / 9;
            const int co = ln & 31, gg = ln >> 5;
            const int ci = cig * 16 + gg * 8 + j;
            const int tap = ql * 27 + qd * 9 + s;
            Ag[i] = f2bf(wgt[((size_t)ci * CC + co) * 81 + 80 - tap]);
        }
    }
}

// Block = (n, l, d-pair, h-half): output planes d0,d0+1, rows hb..hb+11,
// all 24 w, all 32 co. Per staged input plane p (padded dp = d0+p, p=0..3),
// ONE B-read feeds TWO MFMAs (out d0 with qd=p, out d0+1 with qd=p-1).
// A staged at qd-block granularity (9216 B) into a 3-slot rotation;
// slot = qd statically. Stage p reads slots {p-1,p}, prefetches (p+1)%3 --
// disjoint by construction; prefetch lands at next barrier's vmcnt drain.
// LDS = 2x11872 + 3x9216 = 51.4 KB -> 3 blocks/CU.
__global__ __launch_bounds__(192) void convt4d_main(
    const unsigned short* __restrict__ xp, const unsigned short* __restrict__ Ag,
    const float* __restrict__ bias, float* __restrict__ out)
{
    __shared__ __align__(16) unsigned short xs[2][742 * 8];   // 2 x 11,872 B
    __shared__ __align__(16) unsigned short As[3][576 * 8];   // 3 x  9,216 B

    // XCD swizzle: logical-consecutive blocks -> same XCD (768 % 8 == 0)
    int bid = (int)blockIdx.x;
    bid = (bid & 7) * 96 + (bid >> 3);
    // logical: bid = ((n*8 + l)*12 + pd)*2 + hh
    const int hh = bid & 1;
    const int r0 = bid >> 1;
    const int pd = r0 % 12;
    const int r1 = r0 / 12;
    const int l  = r1 & 7;
    const int n  = r1 >> 3;
    const int d0 = pd * 2;
    const int hb = hh * 12;

    const int t    = (int)threadIdx.x;
    const int lane = t & 63;
    const int wave = t >> 6;           // 0..2
    const int g    = lane >> 5;        // ci-half selector
    const int dh   = (lane >> 3) & 3;
    const int dw   = lane & 7;

    const int ql0 = (l == 0) ? 1 : 0;
    const int nql = 3 - (l == 0) - (l == 7);
    const int nst = 8 * nql;           // stages: (cig2, valid ql) x plane p0..3
    const int nq  = 6 * nql;           // total qd-blocks

    f32x16 acc[2][3];
#pragma unroll
    for (int o = 0; o < 2; ++o)
#pragma unroll
        for (int i = 0; i < 3; ++i)
#pragma unroll
            for (int j = 0; j < 16; ++j) acc[o][i][j] = 0.f;

    // per-lane ds_read base (elems): unit = row*53 + wp_local*2 + g
    const int eb = ((wave * 4 + dh) * 53 + dw * 2 + g) * 8;

    // stage one input plane (14 rows x 26 px, ci16) into xs[buf]
    auto issueX = [&](int st, int buf) {
        const int p   = st & 3;
        const int r   = st >> 2;
        const int ql  = ql0 + r % nql;
        const int cig = r / nql;
        const int lx  = l + ql - 1;
        const int dpad = d0 + p;       // padded-d index 0..25
        const size_t base = ((size_t)(((cig * 4 + n) * 8 + lx) * 26) + dpad) * 1352
                          + (size_t)hb * 52;   // 16B-chunk offset
        unsigned short* dst = xs[buf];
#pragma unroll
        for (int k = 0; k < 4; ++k) {
            const int v = t + k * 192;
            if (k < 3 || v < 742) {
                int row = v / 53;          // 14 rows x 53 units (col 52 = pad)
                int su  = v - row;         // source unit (52 units/row)
                if (su > 727) su = 727;
                gload16(xp + (base + su) * 8, (char*)dst + (size_t)v * 16);
            }
        }
    };
    // stage qd-block q (= 3*grp + qd) into slot As[q % 3] (9216 B, 576 chunks)
    auto issueA = [&](int q) {
        const int grp = q / 3, qd = q % 3;
        const int ql  = ql0 + grp % nql;
        const int cig = grp / nql;
        const unsigned short* src = Ag + (size_t)(cig * 9 + ql * 3 + qd) * 4608;
        unsigned short* dst = As[q % 3];
        gload16(src + (size_t)t * 8,         (char*)dst + (size_t)t * 16);
        gload16(src + (size_t)(t + 192) * 8, (char*)dst + (size_t)(t + 192) * 16);
        gload16(src + (size_t)(t + 384) * 8, (char*)dst + (size_t)(t + 384) * 16);
    };

    issueX(0, 0);
    issueA(0);

#pragma unroll 1
    for (int st = 0; st < nst; ++st) {
        const int buf = st & 1;
        const int p   = st & 3;        // input plane = padded dp d0+p
        const int grp = st >> 2;
        __syncthreads();               // stage st landed; prior readers done
        if (st + 1 < nst) issueX(st + 1, buf ^ 1);
        {
            const int qn = 3 * grp + p + 1;     // block first needed at st+1
            if (p < 3 && qn < nq) issueA(qn);
        }

        const unsigned short* xb = xs[buf] + eb;
        // out0 (d0):   qd = p,   valid p<=2   -> slot As[p]
        // out1 (d0+1): qd = p-1, valid p>=1   -> slot As[p-1]
        if (p == 0) {
            const unsigned short* a0b = &As[0][lane * 8];
#pragma unroll
            for (int s = 0; s < 9; ++s) {
                bf16x8 a0 = *reinterpret_cast<const bf16x8*>(a0b + s * 512);
                const int qh = s / 3, qw = s % 3;
                const int o = (qh * 53 + qw * 2) * 8;
#pragma unroll
                for (int nt = 0; nt < 3; ++nt) {
                    bf16x8 b = *reinterpret_cast<const bf16x8*>(xb + o + nt * 128);
                    acc[0][nt] = __builtin_amdgcn_mfma_f32_32x32x16_bf16(a0, b, acc[0][nt], 0, 0, 0);
                }
            }
        } else if (p == 3) {
            const unsigned short* a1b = &As[2][lane * 8];
#pragma unroll
            for (int s = 0; s < 9; ++s) {
                bf16x8 a1 = *reinterpret_cast<const bf16x8*>(a1b + s * 512);
                const int qh = s / 3, qw = s % 3;
                const int o = (qh * 53 + qw * 2) * 8;
#pragma unroll
                for (int nt = 0; nt < 3; ++nt) {
                    bf16x8 b = *reinterpret_cast<const bf16x8*>(xb + o + nt * 128);
                    acc[1][nt] = __builtin_amdgcn_mfma_f32_32x32x16_bf16(a1, b, acc[1][nt], 0, 0, 0);
                }
            }
        } else {
            const unsigned short* a0b = &As[p][lane * 8];
            const unsigned short* a1b = &As[p - 1][lane * 8];
#pragma unroll
            for (int s = 0; s < 9; ++s) {
                bf16x8 a0 = *reinterpret_cast<const bf16x8*>(a0b + s * 512);
                bf16x8 a1 = *reinterpret_cast<const bf16x8*>(a1b + s * 512);
                const int qh = s / 3, qw = s % 3;
                const int o = (qh * 53 + qw * 2) * 8;
#pragma unroll
                for (int nt = 0; nt < 3; ++nt) {
                    bf16x8 b = *reinterpret_cast<const bf16x8*>(xb + o + nt * 128);
                    acc[0][nt] = __builtin_amdgcn_mfma_f32_32x32x16_bf16(a0, b, acc[0][nt], 0, 0, 0);
                    acc[1][nt] = __builtin_amdgcn_mfma_f32_32x32x16_bf16(a1, b, acc[1][nt], 0, 0, 0);
                }
            }
        }
    }

    // ---- epilogue: bias + store (C/D: col=lane&31 -> pos, row -> co) ----
#pragma unroll
    for (int r = 0; r < 16; ++r) {
        const int co = (r & 3) + 8 * (r >> 2) + 4 * g;
        const float bv = bias[co];
#pragma unroll
        for (int o = 0; o < 2; ++o) {
            size_t ob = (((((size_t)n * CC + co) * LL + l) * DD + (d0 + o)) * HH
                       + (hb + wave * 4 + dh)) * WW + dw;
            out[ob]      = acc[o][0][r] + bv;
            out[ob + 8]  = acc[o][1][r] + bv;
            out[ob + 16] = acc[o][2][r] + bv;
        }
    }
}

extern "C" void kernel_launch(void* const* d_in, const int* in_sizes, int n_in,
                              void* d_out, int out_size, void* d_ws, size_t ws_size,
                              hipStream_t stream) {
    const float* x    = (const float*)d_in[0];
    const float* wgt  = (const float*)d_in[1];
    const float* bias = (const float*)d_in[2];
    float* out = (float*)d_out;

    unsigned short* xp = (unsigned short*)d_ws;
    unsigned short* Ag = xp + XP_ELEMS;

    prep<<<(XP_CHUNKS + AG_ELEMS) / 256, 256, 0, stream>>>(x, wgt, xp, Ag);  // 9112 blocks
    convt4d_main<<<768, 192, 0, stream>>>(xp, Ag, bias, out);
}

// Round 10
// 101.661 us; speedup vs baseline: 1.3962x; 1.3962x over previous
//
#include <hip/hip_runtime.h>

#define NN 4
#define CC 32
#define LL 8
#define DD 24
#define HH 24
#define WW 24

typedef short  bf16x8  __attribute__((ext_vector_type(8)));
typedef float  f32x16  __attribute__((ext_vector_type(16)));
typedef unsigned short ushort8 __attribute__((ext_vector_type(8)));

// ws layout (36,161,536 B):
//   xp: [cig 2][n 4][l 8][dp 26][hp 26][wp 26][ci 16] bf16, NO padding
//   Ag: [cig 2][ql 3][qd 3][s 9][lane 64][j 8] bf16 (flipped wgt, frag order)
#define XP_CHUNKS 2249728            // 16B chunks
#define XP_ELEMS  (XP_CHUNKS * 8)
#define AG_ELEMS  82944

__device__ __forceinline__ unsigned short f2bf(float f) {
    union { float f; unsigned u; } v; v.f = f;
    unsigned r = v.u + 0x7FFFu + ((v.u >> 16) & 1u);   // RNE
    return (unsigned short)(r >> 16);
}

__device__ __forceinline__ void gload16(const void* g, void* l) {
    __builtin_amdgcn_global_load_lds(
        (const __attribute__((address_space(1))) unsigned int*)g,
        (__attribute__((address_space(3))) unsigned int*)l, 16, 0, 0);
}

// ---- fused pre-pass: x -> xp and wgt -> Ag (verified R5-R9) ----
__global__ __launch_bounds__(256) void prep(const float* __restrict__ x,
                                            const float* __restrict__ wgt,
                                            unsigned short* __restrict__ xp,
                                            unsigned short* __restrict__ Ag) {
    const int id = blockIdx.x * 256 + threadIdx.x;
    if (id < XP_CHUNKS) {
        const int wp = id % 26;
        const int r  = id / 26;
        const int g  = r & 1;
        const int r2 = r >> 1;             // slab*26 + hp
        const int hp = r2 % 26;
        const int slab = r2 / 26;          // ((cig*4 + n)*8 + l)*26 + dp
        const int dp = slab % 26;
        const int s2 = slab / 26;
        const int l  = s2 & 7;
        const int n  = (s2 >> 3) & 3;
        const int cig = s2 >> 5;
        const int dx = dp - 1, hx = hp - 1, wx = wp - 1;
        ushort8 v = {0, 0, 0, 0, 0, 0, 0, 0};
        if ((unsigned)dx < DD && (unsigned)hx < HH && (unsigned)wx < WW) {
            const int ci0 = cig * 16 + g * 8;
            const float* src = x + ((((size_t)n * CC + ci0) * LL + l) * DD + dx) * (HH * WW)
                             + hx * WW + wx;
#pragma unroll
            for (int ci = 0; ci < 8; ++ci)
                v[ci] = f2bf(src[(size_t)ci * (LL * DD * HH * WW)]);
        }
        const size_t dstc = ((size_t)r2 * 26 + wp) * 2 + g;
        *reinterpret_cast<ushort8*>(xp + dstc * 8) = v;
    } else {
        const int i = id - XP_CHUNKS;
        if (i < AG_ELEMS) {
            const int j  = i & 7;
            const int ln = (i >> 3) & 63;
            const int rest = i >> 9;       // 0..161
            const int s  = rest % 9;
            const int r  = rest / 9;       // cig*9 + ql*3 + qd
            const int qd = r % 3;
            const int ql = (r / 3) % 3;
            const int cig = r / 9;
            const int co = ln & 31, gg = ln >> 5;
            const int ci = cig * 16 + gg * 8 + j;
            const int tap = ql * 27 + qd * 9 + s;
            Ag[i] = f2bf(wgt[((size_t)ci * CC + co) * 81 + 80 - tap]);
        }
    }
}

// GEMM: A[co][k]=flipped wgt (M=32), B[k][pos]=shifted x, K=(ci,tap)=2592.
// K-step = 16 ci x 1 tap -> zero dummy MFMAs (162 exact k-steps interior).
// Block = (n,l,d), 384 thr = 6 waves, wave = 4 h-rows x 24 w x 32 co.
// Stage = one (cig16,ql,qd) plane (53-unit odd-stride rows), double-buffered.
// A: SINGLE LDS buffer + per-stage preload to registers; barrier #2 after
// the preload releases As for the next stage's prefetch. LDS = 53.3 KB ->
// 3 blocks/CU (18 waves) while keeping the ci16 traffic savings.
__global__ __launch_bounds__(384, 4) void convt4d_main(
    const unsigned short* __restrict__ xp, const unsigned short* __restrict__ Ag,
    const float* __restrict__ bias, float* __restrict__ out)
{
    __shared__ __align__(16) unsigned short xs[2][1378 * 8];   // 2 x 22,048 B
    __shared__ __align__(16) unsigned short As[576 * 8];       //     9,216 B

    // XCD-aware bijective swizzle (768 % 8 == 0)
    int bid = (int)blockIdx.x;
    bid = (bid & 7) * 96 + (bid >> 3);
    const int n = bid / (LL * DD);
    const int l = (bid / DD) % LL;
    const int d = bid % DD;

    const int t    = (int)threadIdx.x;
    const int lane = t & 63;
    const int wave = t >> 6;           // 0..5
    const int g    = lane >> 5;        // ci-half selector
    const int dh   = (lane >> 3) & 3;
    const int dw   = lane & 7;
    const int h0   = wave * 4;

    const int ql0 = (l == 0) ? 1 : 0;
    const int nql = 3 - (l == 0) - (l == 7);
    const int nst = 6 * nql;           // stages: (cig2, valid ql, qd3)

    f32x16 acc[3];
#pragma unroll
    for (int i = 0; i < 3; ++i)
#pragma unroll
        for (int j = 0; j < 16; ++j) acc[i][j] = 0.f;

    // per-lane ds_read base (elems): unit = row*53 + wp*2 + g
    const int eb = ((h0 + dh) * 53 + dw * 2 + g) * 8;

    auto issueX = [&](int st, int buf) {
        const int qd  = st % 3;
        const int r   = st / 3;
        const int ql  = ql0 + r % nql;
        const int cig = r / nql;
        const int lx  = l + ql - 1;
        const size_t base = ((size_t)(((cig * 4 + n) * 8 + lx) * 26) + (d + qd)) * 1352;
        unsigned short* dst = xs[buf];
        // linear LDS dst (v*16B); source carries the 53-stride row-pad perm
#pragma unroll
        for (int k = 0; k < 4; ++k) {
            const int v = t + k * 384;
            if (k < 3 || v < 1378) {
                int row = v / 53;
                int su  = v - row;         // src unit (52/row; col 52 = pad)
                if (su > 1351) su = 1351;
                gload16(xp + (base + su) * 8, (char*)dst + (size_t)v * 16);
            }
        }
    };
    auto issueA = [&](int st) {
        const int qd  = st % 3;
        const int r   = st / 3;
        const int ql  = ql0 + r % nql;
        const int cig = r / nql;
        const unsigned short* src = Ag + (size_t)(cig * 9 + ql * 3 + qd) * 4608;
        gload16(src + (size_t)t * 8, (char*)As + (size_t)t * 16);
        if (t < 192)
            gload16(src + (size_t)(t + 384) * 8, (char*)As + (size_t)(t + 384) * 16);
    };

    issueX(0, 0);
    issueA(0);

#pragma unroll 1
    for (int st = 0; st < nst; ++st) {
        const int buf = st & 1;
        __syncthreads();               // #1: X(st)+A(st) landed; xs[buf^1] free

        // ---- preload this stage's 9 A-fragments to registers ----
        bf16x8 A[9];
#pragma unroll
        for (int s = 0; s < 9; ++s)
            A[s] = *reinterpret_cast<const bf16x8*>(&As[(s * 64 + lane) * 8]);
        __syncthreads();               // #2: As consumed -> safe to overwrite

        if (st + 1 < nst) {
            issueX(st + 1, buf ^ 1);
            issueA(st + 1);
        }

        // ---- 9 k-steps (taps) x 3 n-tiles; B from LDS, A from regs ----
        const unsigned short* xb = xs[buf] + eb;
        __builtin_amdgcn_s_setprio(1);
#pragma unroll
        for (int s = 0; s < 9; ++s) {
            const int qh = s / 3, qw = s % 3;
            const int o = (qh * 53 + qw * 2) * 8;    // compile-time imm (shorts)
#pragma unroll
            for (int nt = 0; nt < 3; ++nt) {
                bf16x8 b = *reinterpret_cast<const bf16x8*>(xb + o + nt * 128);
                acc[nt] = __builtin_amdgcn_mfma_f32_32x32x16_bf16(A[s], b, acc[nt], 0, 0, 0);
            }
        }
        __builtin_amdgcn_s_setprio(0);
    }

    // ---- epilogue: bias + store (C/D: col=lane&31 -> pos, row -> co) ----
#pragma unroll
    for (int r = 0; r < 16; ++r) {
        const int co = (r & 3) + 8 * (r >> 2) + 4 * g;
        const float bv = bias[co];
        size_t ob = (((((size_t)n * CC + co) * LL + l) * DD + d) * HH + (h0 + dh)) * WW + dw;
        out[ob]      = acc[0][r] + bv;
        out[ob + 8]  = acc[1][r] + bv;
        out[ob + 16] = acc[2][r] + bv;
    }
}

extern "C" void kernel_launch(void* const* d_in, const int* in_sizes, int n_in,
                              void* d_out, int out_size, void* d_ws, size_t ws_size,
                              hipStream_t stream) {
    const float* x    = (const float*)d_in[0];
    const float* wgt  = (const float*)d_in[1];
    const float* bias = (const float*)d_in[2];
    float* out = (float*)d_out;

    unsigned short* xp = (unsigned short*)d_ws;
    unsigned short* Ag = xp + XP_ELEMS;

    prep<<<(XP_CHUNKS + AG_ELEMS) / 256, 256, 0, stream>>>(x, wgt, xp, Ag);  // 9112 blocks
    convt4d_main<<<NN * LL * DD, 384, 0, stream>>>(xp, Ag, bias, out);
}

// Round 11
// 101.085 us; speedup vs baseline: 1.4042x; 1.0057x over previous
//
#include <hip/hip_runtime.h>

#define NN 4
#define CC 32
#define LL 8
#define DD 24
#define HH 24
#define WW 24

typedef short  bf16x8  __attribute__((ext_vector_type(8)));
typedef float  f32x16  __attribute__((ext_vector_type(16)));
typedef unsigned short ushort8 __attribute__((ext_vector_type(8)));

// ws layout (36,161,536 B):
//   xp: [cig 2][n 4][l 8][dp 26][hp 26][wp 26][ci 16] bf16, NO padding
//   Ag: [cig 2][ql 3][qd 3][s 9][lane 64][j 8] bf16 (flipped wgt, frag order)
#define XP_CHUNKS 2249728            // 16B chunks
#define XP_ELEMS  (XP_CHUNKS * 8)
#define AG_ELEMS  82944

__device__ __forceinline__ unsigned short f2bf(float f) {
    union { float f; unsigned u; } v; v.f = f;
    unsigned r = v.u + 0x7FFFu + ((v.u >> 16) & 1u);   // RNE
    return (unsigned short)(r >> 16);
}

__device__ __forceinline__ void gload16(const void* g, void* l) {
    __builtin_amdgcn_global_load_lds(
        (const __attribute__((address_space(1))) unsigned int*)g,
        (__attribute__((address_space(3))) unsigned int*)l, 16, 0, 0);
}

// ---- fused pre-pass: x -> xp and wgt -> Ag (verified R5-R10) ----
__global__ __launch_bounds__(256) void prep(const float* __restrict__ x,
                                            const float* __restrict__ wgt,
                                            unsigned short* __restrict__ xp,
                                            unsigned short* __restrict__ Ag) {
    const int id = blockIdx.x * 256 + threadIdx.x;
    if (id < XP_CHUNKS) {
        const int wp = id % 26;
        const int r  = id / 26;
        const int g  = r & 1;
        const int r2 = r >> 1;             // slab*26 + hp
        const int hp = r2 % 26;
        const int slab = r2 / 26;          // ((cig*4 + n)*8 + l)*26 + dp
        const int dp = slab % 26;
        const int s2 = slab / 26;
        const int l  = s2 & 7;
        const int n  = (s2 >> 3) & 3;
        const int cig = s2 >> 5;
        const int dx = dp - 1, hx = hp - 1, wx = wp - 1;
        ushort8 v = {0, 0, 0, 0, 0, 0, 0, 0};
        if ((unsigned)dx < DD && (unsigned)hx < HH && (unsigned)wx < WW) {
            const int ci0 = cig * 16 + g * 8;
            const float* src = x + ((((size_t)n * CC + ci0) * LL + l) * DD + dx) * (HH * WW)
                             + hx * WW + wx;
#pragma unroll
            for (int ci = 0; ci < 8; ++ci)
                v[ci] = f2bf(src[(size_t)ci * (LL * DD * HH * WW)]);
        }
        const size_t dstc = ((size_t)r2 * 26 + wp) * 2 + g;
        *reinterpret_cast<ushort8*>(xp + dstc * 8) = v;
    } else {
        const int i = id - XP_CHUNKS;
        if (i < AG_ELEMS) {
            const int j  = i & 7;
            const int ln = (i >> 3) & 63;
            const int rest = i >> 9;       // 0..161
            const int s  = rest % 9;
            const int r  = rest / 9;       // cig*9 + ql*3 + qd
            const int qd = r % 3;
            const int ql = (r / 3) % 3;
            const int cig = r / 9;
            const int co = ln & 31, gg = ln >> 5;
            const int ci = cig * 16 + gg * 8 + j;
            const int tap = ql * 27 + qd * 9 + s;
            Ag[i] = f2bf(wgt[((size_t)ci * CC + co) * 81 + 80 - tap]);
        }
    }
}

// GEMM: A[co][k]=flipped wgt (M=32), B[k][pos]=shifted x, K=(ci,tap)=2592.
// K-step = 16 ci x 1 tap -> zero dummy MFMAs (162 exact k-steps interior).
// Block = (n,l,d), 384 thr = 6 waves, wave = 4 h-rows x 24 w x 32 co.
// Stage = one (cig16,ql,qd) plane (53-unit odd-stride rows), double-buffered.
// A: global->VGPR from L2-resident Ag, issued IMMEDIATELY after the barrier
// and BEFORE the gload_lds prefetch -- vmcnt FIFO then lets the MFMA's wait
// on A leave the prefetch in flight (R5's bug fixed; no launch-bounds cap
// so no R6 spill). LDS = xs dbuf only = 44 KB, ONE barrier per stage.
__global__ __launch_bounds__(384) void convt4d_main(
    const unsigned short* __restrict__ xp, const unsigned short* __restrict__ Ag,
    const float* __restrict__ bias, float* __restrict__ out)
{
    __shared__ __align__(16) unsigned short xs[2][1378 * 8];   // 2 x 22,048 B

    // XCD-aware bijective swizzle (768 % 8 == 0)
    int bid = (int)blockIdx.x;
    bid = (bid & 7) * 96 + (bid >> 3);
    const int n = bid / (LL * DD);
    const int l = (bid / DD) % LL;
    const int d = bid % DD;

    const int t    = (int)threadIdx.x;
    const int lane = t & 63;
    const int wave = t >> 6;           // 0..5
    const int g    = lane >> 5;        // ci-half selector
    const int dh   = (lane >> 3) & 3;
    const int dw   = lane & 7;
    const int h0   = wave * 4;

    const int ql0 = (l == 0) ? 1 : 0;
    const int nql = 3 - (l == 0) - (l == 7);
    const int nst = 6 * nql;           // stages: (cig2, valid ql, qd3)

    f32x16 acc[3];
#pragma unroll
    for (int i = 0; i < 3; ++i)
#pragma unroll
        for (int j = 0; j < 16; ++j) acc[i][j] = 0.f;

    // per-lane ds_read base (elems): unit = row*53 + wp*2 + g
    const int eb = ((h0 + dh) * 53 + dw * 2 + g) * 8;

    auto issueX = [&](int st, int buf) {
        const int qd  = st % 3;
        const int r   = st / 3;
        const int ql  = ql0 + r % nql;
        const int cig = r / nql;
        const int lx  = l + ql - 1;
        const size_t base = ((size_t)(((cig * 4 + n) * 8 + lx) * 26) + (d + qd)) * 1352;
        unsigned short* dst = xs[buf];
        // linear LDS dst (v*16B); source carries the 53-stride row-pad perm
#pragma unroll
        for (int k = 0; k < 4; ++k) {
            const int v = t + k * 384;
            if (k < 3 || v < 1378) {
                int row = v / 53;
                int su  = v - row;         // src unit (52/row; col 52 = pad)
                if (su > 1351) su = 1351;
                gload16(xp + (base + su) * 8, (char*)dst + (size_t)v * 16);
            }
        }
    };

    issueX(0, 0);

#pragma unroll 1
    for (int st = 0; st < nst; ++st) {
        const int buf = st & 1;
        __syncthreads();               // stage st landed; xs[buf^1] free

        // ---- A fragments for stage st: global->VGPR, issued FIRST so the
        //      MFMA's vmcnt wait on A leaves the prefetch in flight ----
        const int qd  = st % 3;
        const int r   = st / 3;
        const int ql  = ql0 + r % nql;
        const int cig = r / nql;
        const unsigned short* ab =
            Ag + (size_t)(cig * 9 + ql * 3 + qd) * 4608 + lane * 8;
        bf16x8 A[9];
#pragma unroll
        for (int s = 0; s < 9; ++s)
            A[s] = *reinterpret_cast<const bf16x8*>(ab + s * 512);
        __builtin_amdgcn_sched_barrier(0);   // pin: A-loads before prefetch

        if (st + 1 < nst) issueX(st + 1, buf ^ 1);
        __builtin_amdgcn_sched_barrier(0);   // pin: prefetch issued before compute

        // ---- 9 k-steps (taps) x 3 n-tiles; B from LDS, A from regs ----
        const unsigned short* xb = xs[buf] + eb;
        __builtin_amdgcn_s_setprio(1);
#pragma unroll
        for (int s = 0; s < 9; ++s) {
            const int qh = s / 3, qw = s % 3;
            const int o = (qh * 53 + qw * 2) * 8;    // compile-time imm (shorts)
#pragma unroll
            for (int nt = 0; nt < 3; ++nt) {
                bf16x8 b = *reinterpret_cast<const bf16x8*>(xb + o + nt * 128);
                acc[nt] = __builtin_amdgcn_mfma_f32_32x32x16_bf16(A[s], b, acc[nt], 0, 0, 0);
            }
        }
        __builtin_amdgcn_s_setprio(0);
    }

    // ---- epilogue: bias + store (C/D: col=lane&31 -> pos, row -> co) ----
#pragma unroll
    for (int r = 0; r < 16; ++r) {
        const int co = (r & 3) + 8 * (r >> 2) + 4 * g;
        const float bv = bias[co];
        size_t ob = (((((size_t)n * CC + co) * LL + l) * DD + d) * HH + (h0 + dh)) * WW + dw;
        out[ob]      = acc[0][r] + bv;
        out[ob + 8]  = acc[1][r] + bv;
        out[ob + 16] = acc[2][r] + bv;
    }
}

extern "C" void kernel_launch(void* const* d_in, const int* in_sizes, int n_in,
                              void* d_out, int out_size, void* d_ws, size_t ws_size,
                              hipStream_t stream) {
    const float* x    = (const float*)d_in[0];
    const float* wgt  = (const float*)d_in[1];
    const float* bias = (const float*)d_in[2];
    float* out = (float*)d_out;

    unsigned short* xp = (unsigned short*)d_ws;
    unsigned short* Ag = xp + XP_ELEMS;

    prep<<<(XP_CHUNKS + AG_ELEMS) / 256, 256, 0, stream>>>(x, wgt, xp, Ag);  // 9112 blocks
    convt4d_main<<<NN * LL * DD, 384, 0, stream>>>(xp, Ag, bias, out);
}